// Round 1
// baseline (596.221 us; speedup 1.0000x reference)
//
#include <hip/hip_runtime.h>

typedef __attribute__((ext_vector_type(8))) short short8;
typedef __attribute__((ext_vector_type(4))) float f32x4;

#define DEV __device__ __forceinline__

DEV unsigned short f2bf(float f) {
    unsigned int u = __builtin_bit_cast(unsigned int, f);
    u += 0x7fffu + ((u >> 16) & 1u);
    return (unsigned short)(u >> 16);
}

// ---------------------------------------------------------------- stats ----
// One wave per 1024-float row; rows [0,4096) = hidden, [4096,36864) = inputs.
__global__ __launch_bounds__(256) void stats_kernel(
    const float* __restrict__ hidden, const float* __restrict__ inputs,
    float2* __restrict__ statsH, float2* __restrict__ statsX)
{
    int row = blockIdx.x * 4 + (threadIdx.x >> 6);
    int lane = threadIdx.x & 63;
    const float* src;
    float2* dst;
    if (row < 4096) { src = hidden + (size_t)row * 1024; dst = statsH + row; }
    else            { src = inputs + (size_t)(row - 4096) * 1024; dst = statsX + (row - 4096); }
    float s = 0.f, ss = 0.f;
#pragma unroll
    for (int i = 0; i < 4; ++i) {
        f32x4 v = *reinterpret_cast<const f32x4*>(src + i * 256 + lane * 4);
#pragma unroll
        for (int j = 0; j < 4; ++j) { s += v[j]; ss += v[j] * v[j]; }
    }
#pragma unroll
    for (int off = 32; off >= 1; off >>= 1) {
        s  += __shfl_xor(s, off);
        ss += __shfl_xor(ss, off);
    }
    if (lane == 0) {
        float mu  = s * (1.f / 1024.f);
        float var = fmaxf(ss * (1.f / 1024.f) - mu * mu, 0.f);
        float2 r; r.x = mu; r.y = rsqrtf(var + 1e-5f);
        *dst = r;
    }
}

// ------------------------------------------------------------- convert ----
// fp32 -> bf16 for the three 1024x1024 weight matrices. 393216 threads.
__global__ __launch_bounds__(256) void convert_w(
    const float* __restrict__ Wq, const float* __restrict__ Wk, const float* __restrict__ Wv,
    unsigned short* __restrict__ oq, unsigned short* __restrict__ ok_, unsigned short* __restrict__ ov)
{
    unsigned tid = blockIdx.x * 256 + threadIdx.x;
    int arr = tid >> 17;                       // 131072 threads per array
    size_t off = (size_t)(tid & 131071u) * 8;
    const float* s = (arr == 0) ? Wq : (arr == 1) ? Wk : Wv;
    unsigned short* d = (arr == 0) ? oq : (arr == 1) ? ok_ : ov;
    f32x4 a = *reinterpret_cast<const f32x4*>(s + off);
    f32x4 b = *reinterpret_cast<const f32x4*>(s + off + 4);
    short8 r;
#pragma unroll
    for (int j = 0; j < 4; ++j) { r[j] = (short)f2bf(a[j]); r[j + 4] = (short)f2bf(b[j]); }
    *reinterpret_cast<short8*>(d + off) = r;
}

// ---------------------------------------------------------------- GEMM ----
// C[m,n] = sum_k LN(A)[m,k] * W[n,k] + bias[n], output bf16.
// 128x128 tile, BK=64, 4 waves (2x2), each wave 4x4 16x16x32 fragments.
// LN fused into A staging (per-row stats + per-col ln w/b).
DEV int swz64(int row, int col) { return (row * 64 + col) ^ ((row & 7) << 3); }

__global__ __launch_bounds__(256) void gemm_ln(
    const float* __restrict__ A, const float2* __restrict__ stats,
    const float* __restrict__ lnw, const float* __restrict__ lnb,
    const unsigned short* __restrict__ W0, const float* __restrict__ bias0, unsigned short* __restrict__ C0,
    const unsigned short* __restrict__ W1, const float* __restrict__ bias1, unsigned short* __restrict__ C1,
    int nsplit)
{
    __shared__ __align__(16) unsigned short smem[16384];   // Al[128][64] + Bl[128][64], reused as Ct[128][128]
    unsigned short* Al = smem;
    unsigned short* Bl = smem + 8192;

    int t = threadIdx.x, lane = t & 63, wvi = t >> 6;
    int wr = wvi >> 1, wc = wvi & 1, g = lane >> 4, lr = lane & 15;
    int m0 = blockIdx.x * 128;
    int by = blockIdx.y;
    const unsigned short* W; const float* bias; unsigned short* C; int n0;
    if (by < nsplit) { W = W0; bias = bias0; C = C0; n0 = by * 128; }
    else             { W = W1; bias = bias1; C = C1; n0 = (by - nsplit) * 128; }

    f32x4 acc[4][4];
#pragma unroll
    for (int i = 0; i < 4; ++i)
#pragma unroll
        for (int j = 0; j < 4; ++j) acc[i][j] = (f32x4)0.f;

    int srow = t >> 3;          // 0..31
    int scol = (t & 7) * 8;     // 0..56

    for (int kb = 0; kb < 1024; kb += 64) {
        f32x4 w0 = *reinterpret_cast<const f32x4*>(lnw + kb + scol);
        f32x4 w1 = *reinterpret_cast<const f32x4*>(lnw + kb + scol + 4);
        f32x4 b0 = *reinterpret_cast<const f32x4*>(lnb + kb + scol);
        f32x4 b1 = *reinterpret_cast<const f32x4*>(lnb + kb + scol + 4);
        // stage A (fp32 -> LN -> bf16)
#pragma unroll
        for (int i = 0; i < 4; ++i) {
            int row = i * 32 + srow;
            const float* src = A + (size_t)(m0 + row) * 1024 + kb + scol;
            f32x4 a0 = *reinterpret_cast<const f32x4*>(src);
            f32x4 a1 = *reinterpret_cast<const f32x4*>(src + 4);
            float2 st = stats[m0 + row];
            short8 v;
#pragma unroll
            for (int j = 0; j < 4; ++j) {
                v[j]     = (short)f2bf((a0[j] - st.x) * st.y * w0[j] + b0[j]);
                v[j + 4] = (short)f2bf((a1[j] - st.x) * st.y * w1[j] + b1[j]);
            }
            *reinterpret_cast<short8*>(&Al[swz64(row, scol)]) = v;
        }
        // stage B (bf16 weights)
#pragma unroll
        for (int i = 0; i < 4; ++i) {
            int row = i * 32 + srow;
            short8 wv8 = *reinterpret_cast<const short8*>(W + (size_t)(n0 + row) * 1024 + kb + scol);
            *reinterpret_cast<short8*>(&Bl[swz64(row, scol)]) = wv8;
        }
        __syncthreads();
#pragma unroll
        for (int kk = 0; kk < 2; ++kk) {
            int colk = kk * 32 + g * 8;
            short8 af[4], bf[4];
#pragma unroll
            for (int mi = 0; mi < 4; ++mi)
                af[mi] = *reinterpret_cast<const short8*>(&Al[swz64(wr * 64 + mi * 16 + lr, colk)]);
#pragma unroll
            for (int ni = 0; ni < 4; ++ni)
                bf[ni] = *reinterpret_cast<const short8*>(&Bl[swz64(wc * 64 + ni * 16 + lr, colk)]);
#pragma unroll
            for (int mi = 0; mi < 4; ++mi)
#pragma unroll
                for (int ni = 0; ni < 4; ++ni)
                    acc[mi][ni] = __builtin_amdgcn_mfma_f32_16x16x32_bf16(af[mi], bf[ni], acc[mi][ni], 0, 0, 0);
        }
        __syncthreads();
    }

    // epilogue: acc -> LDS (bf16) -> coalesced 16B global stores
    unsigned short* Ct = smem;   // [128][128]
#pragma unroll
    for (int ni = 0; ni < 4; ++ni) {
        int coll = wc * 64 + ni * 16 + lr;
        float bv = bias[n0 + coll];
#pragma unroll
        for (int mi = 0; mi < 4; ++mi)
#pragma unroll
            for (int j = 0; j < 4; ++j) {
                int rowl = wr * 64 + mi * 16 + g * 4 + j;
                Ct[rowl * 128 + coll] = f2bf(acc[mi][ni][j] + bv);
            }
    }
    __syncthreads();
#pragma unroll
    for (int i = 0; i < 8; ++i) {
        int idx = i * 2048 + t * 8;
        int row = idx >> 7, col = idx & 127;
        short8 v = *reinterpret_cast<const short8*>(&Ct[idx]);
        *reinterpret_cast<short8*>(C + (size_t)(m0 + row) * 1024 + n0 + col) = v;
    }
}

// ----------------------------------------------------------- attention ----
// One block per (b, h, q-tile of 128). 4 waves x 32 q-rows. KVBLK = 64.
DEV int kswz(int row, int col) { return (row * 128 + col) ^ ((row & 7) << 3); }          // Kl [64][128]
DEV int pswz(int row, int col) { return (row * 64 + col) ^ ((row & 7) << 3); }           // Pl [128][64]
DEV int vswz(int d, int kv)    { return (d * 72 + kv) ^ (((d >> 3) & 7) << 3); }         // Vt [128][72]

__global__ __launch_bounds__(256, 1) void attn_kernel(
    const unsigned short* __restrict__ Qm, const unsigned short* __restrict__ Km,
    const unsigned short* __restrict__ Vm, const float* __restrict__ hidden,
    float* __restrict__ out)
{
    __shared__ __align__(16) unsigned short Kl[64 * 128];
    __shared__ __align__(16) unsigned short Vt[128 * 72];
    __shared__ __align__(16) unsigned short Pl[128 * 64];

    int t = threadIdx.x, lane = t & 63, w = t >> 6, g = lane >> 4, lr = lane & 15;
    int qt = blockIdx.x, h = blockIdx.y, b = blockIdx.z;
    int q0 = qt * 128 + w * 32;

    // Q fragments in registers: 32 q-rows x 128 d per wave
    short8 qf[2][4];
#pragma unroll
    for (int mi = 0; mi < 2; ++mi)
#pragma unroll
        for (int kk = 0; kk < 4; ++kk)
            qf[mi][kk] = *reinterpret_cast<const short8*>(
                Qm + (size_t)(b * 512 + q0 + mi * 16 + lr) * 1024 + h * 128 + kk * 32 + g * 8);

    float m_r[2][4], l_r[2][4];
    f32x4 oacc[2][8];
#pragma unroll
    for (int mi = 0; mi < 2; ++mi) {
#pragma unroll
        for (int r = 0; r < 4; ++r) { m_r[mi][r] = -__builtin_inff(); l_r[mi][r] = 0.f; }
#pragma unroll
        for (int nf = 0; nf < 8; ++nf) oacc[mi][nf] = (f32x4)0.f;
    }

    const float SCALE = 0.08838834764831845f;   // 1/sqrt(128)
    const float LOG2E = 1.4426950408889634f;
    const float K1 = SCALE * LOG2E;

    size_t kvrow0 = (size_t)b * 4096;

    for (int c = 0; c < 64; ++c) {
        int kv0 = c * 64;
        // stage K [64 kv][128 d], swizzled
#pragma unroll
        for (int i = 0; i < 4; ++i) {
            int idx = i * 256 + t;
            int row = idx >> 4, c8 = (idx & 15) * 8;
            short8 v = *reinterpret_cast<const short8*>(
                Km + (kvrow0 + kv0 + row) * 1024 + h * 128 + c8);
            *reinterpret_cast<short8*>(&Kl[kswz(row, c8)]) = v;
        }
        // stage V transposed: Vt[d][kv]
#pragma unroll
        for (int i = 0; i < 2; ++i) {
            int p = i * 256 + t;
            int kvp = p >> 4, c8 = (p & 15) * 8;
            const unsigned short* vp = Vm + (kvrow0 + kv0 + 2 * kvp) * 1024 + h * 128 + c8;
            short8 v0 = *reinterpret_cast<const short8*>(vp);
            short8 v1 = *reinterpret_cast<const short8*>(vp + 1024);
#pragma unroll
            for (int j = 0; j < 8; ++j) {
                unsigned int pk = (unsigned int)(unsigned short)v0[j] |
                                  ((unsigned int)(unsigned short)v1[j] << 16);
                *reinterpret_cast<unsigned int*>(&Vt[vswz(c8 + j, 2 * kvp)]) = pk;
            }
        }
        __syncthreads();

        // S = Q K^T  (per wave: 32 q x 64 kv)
        f32x4 sacc[2][4];
#pragma unroll
        for (int mi = 0; mi < 2; ++mi)
#pragma unroll
            for (int nf = 0; nf < 4; ++nf) sacc[mi][nf] = (f32x4)0.f;
#pragma unroll
        for (int kk = 0; kk < 4; ++kk) {
            int colk = kk * 32 + g * 8;
            short8 bfr[4];
#pragma unroll
            for (int nf = 0; nf < 4; ++nf)
                bfr[nf] = *reinterpret_cast<const short8*>(&Kl[kswz(nf * 16 + lr, colk)]);
#pragma unroll
            for (int mi = 0; mi < 2; ++mi)
#pragma unroll
                for (int nf = 0; nf < 4; ++nf)
                    sacc[mi][nf] = __builtin_amdgcn_mfma_f32_16x16x32_bf16(qf[mi][kk], bfr[nf], sacc[mi][nf], 0, 0, 0);
        }

        // online softmax (C layout: row = g*4+r, col = lane&15)
#pragma unroll
        for (int mi = 0; mi < 2; ++mi) {
#pragma unroll
            for (int r = 0; r < 4; ++r) {
                float rowmax = -__builtin_inff();
#pragma unroll
                for (int nf = 0; nf < 4; ++nf) rowmax = fmaxf(rowmax, sacc[mi][nf][r]);
                rowmax *= SCALE;
#pragma unroll
                for (int off = 1; off < 16; off <<= 1)
                    rowmax = fmaxf(rowmax, __shfl_xor(rowmax, off));
                float mold = m_r[mi][r];
                float mnew = fmaxf(mold, rowmax);
                float corr = exp2f((mold - mnew) * LOG2E);
                float mn2 = mnew * LOG2E;
                float rsum = 0.f;
                int prow = w * 32 + mi * 16 + g * 4 + r;
#pragma unroll
                for (int nf = 0; nf < 4; ++nf) {
                    float p = exp2f(sacc[mi][nf][r] * K1 - mn2);
                    rsum += p;
                    Pl[pswz(prow, nf * 16 + lr)] = f2bf(p);
                }
#pragma unroll
                for (int off = 1; off < 16; off <<= 1)
                    rsum += __shfl_xor(rsum, off);
                l_r[mi][r] = l_r[mi][r] * corr + rsum;
                m_r[mi][r] = mnew;
#pragma unroll
                for (int nf = 0; nf < 8; ++nf) oacc[mi][nf][r] *= corr;
            }
        }
        asm volatile("s_waitcnt lgkmcnt(0)" ::: "memory");   // P writes -> own-wave reads

        // O += P V   (per wave: 32 q x 128 d, K-dim = 64 kv)
#pragma unroll
        for (int kp = 0; kp < 2; ++kp) {
            int colp = kp * 32 + g * 8;
            short8 pa[2];
#pragma unroll
            for (int mi = 0; mi < 2; ++mi)
                pa[mi] = *reinterpret_cast<const short8*>(&Pl[pswz(w * 32 + mi * 16 + lr, colp)]);
#pragma unroll
            for (int nf = 0; nf < 8; ++nf) {
                short8 vb = *reinterpret_cast<const short8*>(&Vt[vswz(nf * 16 + lr, colp)]);
#pragma unroll
                for (int mi = 0; mi < 2; ++mi)
                    oacc[mi][nf] = __builtin_amdgcn_mfma_f32_16x16x32_bf16(pa[mi], vb, oacc[mi][nf], 0, 0, 0);
            }
        }
        __syncthreads();   // before next chunk overwrites Kl/Vt
    }

    // epilogue: out = hidden + O / l
#pragma unroll
    for (int mi = 0; mi < 2; ++mi)
#pragma unroll
        for (int r = 0; r < 4; ++r) {
            float inv = 1.f / l_r[mi][r];
            int q = qt * 128 + w * 32 + mi * 16 + g * 4 + r;
            size_t base = (size_t)(b * 512 + q) * 1024 + h * 128;
#pragma unroll
            for (int nf = 0; nf < 8; ++nf) {
                int d = nf * 16 + lr;
                out[base + d] = hidden[base + d] + oacc[mi][nf][r] * inv;
            }
        }
}

// ---------------------------------------------------------------- host ----
extern "C" void kernel_launch(void* const* d_in, const int* in_sizes, int n_in,
                              void* d_out, int out_size, void* d_ws, size_t ws_size,
                              hipStream_t stream) {
    const float* hidden = (const float*)d_in[0];
    const float* inputs = (const float*)d_in[1];
    const float* ln1w   = (const float*)d_in[2];
    const float* ln1b   = (const float*)d_in[3];
    const float* ln2w   = (const float*)d_in[4];
    const float* ln2b   = (const float*)d_in[5];
    const float* Wq     = (const float*)d_in[6];
    const float* bq     = (const float*)d_in[7];
    const float* Wk     = (const float*)d_in[8];
    const float* bk     = (const float*)d_in[9];
    const float* Wv     = (const float*)d_in[10];
    const float* bv     = (const float*)d_in[11];
    float* out = (float*)d_out;

    char* ws = (char*)d_ws;
    float2* statsH = (float2*)ws;                         // 4096 * 8 B
    float2* statsX = (float2*)(ws + 32768);               // 32768 * 8 B
    unsigned short* WqB = (unsigned short*)(ws + 294912); // 3 x 1M bf16
    unsigned short* WkB = WqB + 1048576;
    unsigned short* WvB = WkB + 1048576;
    unsigned short* Qm  = WvB + 1048576;                  // 4096 x 1024 bf16
    unsigned short* Km  = Qm + 4194304;                   // 32768 x 1024 bf16
    unsigned short* Vm  = Km + 33554432;                  // 32768 x 1024 bf16

    stats_kernel<<<dim3(9216), dim3(256), 0, stream>>>(hidden, inputs, statsH, statsX);
    convert_w<<<dim3(1536), dim3(256), 0, stream>>>(Wq, Wk, Wv, WqB, WkB, WvB);
    gemm_ln<<<dim3(32, 8), dim3(256), 0, stream>>>(
        hidden, statsH, ln1w, ln1b, WqB, bq, Qm, WqB, bq, Qm, 8);
    gemm_ln<<<dim3(256, 16), dim3(256), 0, stream>>>(
        inputs, statsX, ln2w, ln2b, WkB, bk, Km, WvB, bv, Vm, 8);
    attn_kernel<<<dim3(4, 8, 8), dim3(256), 0, stream>>>(Qm, Km, Vm, hidden, out);
}

// Round 3
// 460.469 us; speedup vs baseline: 1.2948x; 1.2948x over previous
//
#include <hip/hip_runtime.h>

typedef __attribute__((ext_vector_type(8))) short short8;
typedef __attribute__((ext_vector_type(4))) short bf16x4;
typedef __attribute__((ext_vector_type(4))) float f32x4;

#define DEV __device__ __forceinline__

DEV unsigned short f2bf(float f) {
    unsigned int u = __builtin_bit_cast(unsigned int, f);
    u += 0x7fffu + ((u >> 16) & 1u);
    return (unsigned short)(u >> 16);
}

#define GLOAD16(gp, lp)                                                        \
    __builtin_amdgcn_global_load_lds(                                          \
        (const __attribute__((address_space(1))) void*)(gp),                   \
        (__attribute__((address_space(3))) void*)(lp), 16, 0, 0)

// ------------------------------------------------------------- ln_bf16 ----
// One wave per 1024-float row. rows [0,4096) = hidden->LNh, rest = inputs->LNx.
__global__ __launch_bounds__(256) void ln_bf16(
    const float* __restrict__ hidden, const float* __restrict__ inputs,
    const float* __restrict__ ln1w, const float* __restrict__ ln1b,
    const float* __restrict__ ln2w, const float* __restrict__ ln2b,
    unsigned short* __restrict__ LNh, unsigned short* __restrict__ LNx)
{
    int row = blockIdx.x * 4 + (threadIdx.x >> 6);
    int lane = threadIdx.x & 63;
    const float *src, *wp, *bp; unsigned short* dst;
    if (row < 4096) { src = hidden + (size_t)row * 1024; wp = ln1w; bp = ln1b; dst = LNh + (size_t)row * 1024; }
    else { int r = row - 4096; src = inputs + (size_t)r * 1024; wp = ln2w; bp = ln2b; dst = LNx + (size_t)r * 1024; }

    f32x4 v[4];
    float s = 0.f, ss = 0.f;
#pragma unroll
    for (int i = 0; i < 4; ++i) {
        v[i] = *reinterpret_cast<const f32x4*>(src + i * 256 + lane * 4);
#pragma unroll
        for (int j = 0; j < 4; ++j) { s += v[i][j]; ss += v[i][j] * v[i][j]; }
    }
#pragma unroll
    for (int off = 32; off >= 1; off >>= 1) { s += __shfl_xor(s, off); ss += __shfl_xor(ss, off); }
    float mu = s * (1.f / 1024.f);
    float var = fmaxf(ss * (1.f / 1024.f) - mu * mu, 0.f);
    float rs = rsqrtf(var + 1e-5f);
#pragma unroll
    for (int i = 0; i < 4; ++i) {
        f32x4 wv = *reinterpret_cast<const f32x4*>(wp + i * 256 + lane * 4);
        f32x4 bv = *reinterpret_cast<const f32x4*>(bp + i * 256 + lane * 4);
        bf16x4 o;
#pragma unroll
        for (int j = 0; j < 4; ++j) o[j] = (short)f2bf((v[i][j] - mu) * rs * wv[j] + bv[j]);
        *reinterpret_cast<bf16x4*>(dst + i * 256 + lane * 4) = o;
    }
}

// ------------------------------------------------------------- convert ----
__global__ __launch_bounds__(256) void convert_w(
    const float* __restrict__ Wq, const float* __restrict__ Wk, const float* __restrict__ Wv,
    unsigned short* __restrict__ oq, unsigned short* __restrict__ ok_, unsigned short* __restrict__ ov)
{
    unsigned tid = blockIdx.x * 256 + threadIdx.x;
    int arr = tid >> 17;
    size_t off = (size_t)(tid & 131071u) * 8;
    const float* s = (arr == 0) ? Wq : (arr == 1) ? Wk : Wv;
    unsigned short* d = (arr == 0) ? oq : (arr == 1) ? ok_ : ov;
    f32x4 a = *reinterpret_cast<const f32x4*>(s + off);
    f32x4 b = *reinterpret_cast<const f32x4*>(s + off + 4);
    short8 r;
#pragma unroll
    for (int j = 0; j < 4; ++j) { r[j] = (short)f2bf(a[j]); r[j + 4] = (short)f2bf(b[j]); }
    *reinterpret_cast<short8*>(d + off) = r;
}

// --------------------------------------------------------- gemm_bt (m97) ----
// C[m,n] = sum_k A[m,k] * W[n,k] + bias[n]; A,W bf16 K-major (lda/ldw = 1024).
// 128x128 tile, BK=64, 4 waves (2x2), global_load_lds(16B) staging,
// XOR-swizzle: LDS dest linear, global source pre-swizzled, ds_read swizzled.
__global__ __launch_bounds__(256) void gemm_bt(
    const unsigned short* __restrict__ A,
    const unsigned short* __restrict__ W0, const float* __restrict__ bias0, unsigned short* __restrict__ C0,
    const unsigned short* __restrict__ W1, const float* __restrict__ bias1, unsigned short* __restrict__ C1,
    int nsplit)
{
    __shared__ __align__(16) unsigned short smem[16384];   // As[128][64] + Bs[128][64]; reused as Ct[128][128]
    unsigned short* As = smem;
    unsigned short* Bs = smem + 8192;

    int t = threadIdx.x, lane = t & 63, w = t >> 6;
    int wr = w >> 1, wc = w & 1, g = lane >> 4, lr = lane & 15;
    int m0 = blockIdx.x * 128;
    int by = blockIdx.y;
    const unsigned short* W; const float* bias; unsigned short* C; int n0;
    if (by < nsplit) { W = W0; bias = bias0; C = C0; n0 = by * 128; }
    else             { W = W1; bias = bias1; C = C1; n0 = (by - nsplit) * 128; }

    f32x4 acc[4][4];
#pragma unroll
    for (int i = 0; i < 4; ++i)
#pragma unroll
        for (int j = 0; j < 4; ++j) acc[i][j] = (f32x4)0.f;

    int srow = lane >> 3;              // 0..7 (row within wave's 8-row chunk)
    int scb  = (lane & 7) * 16;        // byte col within 128B row

    for (int kb = 0; kb < 1024; kb += 64) {
#pragma unroll
        for (int i = 0; i < 4; ++i) {
            int row = i * 32 + w * 8 + srow;
            int cb = scb ^ ((row & 7) << 4);          // pre-swizzled source col
            const char* ga = (const char*)(A + (size_t)(m0 + row) * 1024 + kb) + cb;
            GLOAD16(ga, &As[(size_t)(i * 32 + w * 8) * 64]);
            const char* gb = (const char*)(W + (size_t)(n0 + row) * 1024 + kb) + cb;
            GLOAD16(gb, &Bs[(size_t)(i * 32 + w * 8) * 64]);
        }
        __syncthreads();
#pragma unroll
        for (int kk = 0; kk < 2; ++kk) {
            int cb0 = kk * 64 + g * 16;               // byte col of fragment
            short8 af[4], bf[4];
#pragma unroll
            for (int mi = 0; mi < 4; ++mi) {
                int row = wr * 64 + mi * 16 + lr;
                af[mi] = *reinterpret_cast<const short8*>(
                    (const char*)As + row * 128 + (cb0 ^ ((row & 7) << 4)));
            }
#pragma unroll
            for (int ni = 0; ni < 4; ++ni) {
                int row = wc * 64 + ni * 16 + lr;
                bf[ni] = *reinterpret_cast<const short8*>(
                    (const char*)Bs + row * 128 + (cb0 ^ ((row & 7) << 4)));
            }
#pragma unroll
            for (int mi = 0; mi < 4; ++mi)
#pragma unroll
                for (int ni = 0; ni < 4; ++ni)
                    acc[mi][ni] = __builtin_amdgcn_mfma_f32_16x16x32_bf16(af[mi], bf[ni], acc[mi][ni], 0, 0, 0);
        }
        __syncthreads();
    }

    // epilogue
    unsigned short* Ct = smem;
#pragma unroll
    for (int ni = 0; ni < 4; ++ni) {
        int coll = wc * 64 + ni * 16 + lr;
        float bv = bias[n0 + coll];
#pragma unroll
        for (int mi = 0; mi < 4; ++mi)
#pragma unroll
            for (int j = 0; j < 4; ++j) {
                int rowl = wr * 64 + mi * 16 + g * 4 + j;
                Ct[rowl * 128 + coll] = f2bf(acc[mi][ni][j] + bv);
            }
    }
    __syncthreads();
#pragma unroll
    for (int i = 0; i < 8; ++i) {
        int idx = i * 2048 + t * 8;
        int row = idx >> 7, col = idx & 127;
        *reinterpret_cast<short8*>(C + (size_t)(m0 + row) * 1024 + n0 + col) =
            *reinterpret_cast<const short8*>(&Ct[idx]);
    }
}

// ----------------------------------------------------------- attention ----
DEV int kswz(int row, int col) { return (row * 128 + col) ^ ((row & 7) << 3); }
DEV int pswz(int row, int col) { return (row * 64 + col) ^ ((row & 7) << 3); }
DEV int vswz(int d, int kv)    { return (d * 72 + kv) ^ (((d >> 3) & 7) << 3); }

__global__ __launch_bounds__(256, 1) void attn_kernel(
    const unsigned short* __restrict__ Qm, const unsigned short* __restrict__ Km,
    const unsigned short* __restrict__ Vm, const float* __restrict__ hidden,
    float* __restrict__ out)
{
    __shared__ __align__(16) unsigned short Kl[64 * 128];
    __shared__ __align__(16) unsigned short Vt[128 * 72];
    __shared__ __align__(16) unsigned short Pl[128 * 64];

    int t = threadIdx.x, lane = t & 63, w = t >> 6, g = lane >> 4, lr = lane & 15;
    int qt = blockIdx.x, h = blockIdx.y, b = blockIdx.z;
    int q0 = qt * 128 + w * 32;

    short8 qf[2][4];
#pragma unroll
    for (int mi = 0; mi < 2; ++mi)
#pragma unroll
        for (int kk = 0; kk < 4; ++kk)
            qf[mi][kk] = *reinterpret_cast<const short8*>(
                Qm + (size_t)(b * 512 + q0 + mi * 16 + lr) * 1024 + h * 128 + kk * 32 + g * 8);

    float m_r[2][4], l_r[2][4];
    f32x4 oacc[2][8];
#pragma unroll
    for (int mi = 0; mi < 2; ++mi) {
#pragma unroll
        for (int r = 0; r < 4; ++r) { m_r[mi][r] = -__builtin_inff(); l_r[mi][r] = 0.f; }
#pragma unroll
        for (int nf = 0; nf < 8; ++nf) oacc[mi][nf] = (f32x4)0.f;
    }

    const float SCALE = 0.08838834764831845f;
    const float LOG2E = 1.4426950408889634f;
    const float K1 = SCALE * LOG2E;
    size_t kvrow0 = (size_t)b * 4096;

    for (int c = 0; c < 64; ++c) {
        int kv0 = c * 64;
#pragma unroll
        for (int i = 0; i < 4; ++i) {
            int idx = i * 256 + t;
            int row = idx >> 4, c8 = (idx & 15) * 8;
            short8 v = *reinterpret_cast<const short8*>(
                Km + (kvrow0 + kv0 + row) * 1024 + h * 128 + c8);
            *reinterpret_cast<short8*>(&Kl[kswz(row, c8)]) = v;
        }
#pragma unroll
        for (int i = 0; i < 2; ++i) {
            int p = i * 256 + t;
            int kvp = p >> 4, c8 = (p & 15) * 8;
            const unsigned short* vp = Vm + (kvrow0 + kv0 + 2 * kvp) * 1024 + h * 128 + c8;
            short8 v0 = *reinterpret_cast<const short8*>(vp);
            short8 v1 = *reinterpret_cast<const short8*>(vp + 1024);
#pragma unroll
            for (int j = 0; j < 8; ++j) {
                unsigned int pk = (unsigned int)(unsigned short)v0[j] |
                                  ((unsigned int)(unsigned short)v1[j] << 16);
                *reinterpret_cast<unsigned int*>(&Vt[vswz(c8 + j, 2 * kvp)]) = pk;
            }
        }
        __syncthreads();

        f32x4 sacc[2][4];
#pragma unroll
        for (int mi = 0; mi < 2; ++mi)
#pragma unroll
            for (int nf = 0; nf < 4; ++nf) sacc[mi][nf] = (f32x4)0.f;
#pragma unroll
        for (int kk = 0; kk < 4; ++kk) {
            int colk = kk * 32 + g * 8;
            short8 bfr[4];
#pragma unroll
            for (int nf = 0; nf < 4; ++nf)
                bfr[nf] = *reinterpret_cast<const short8*>(&Kl[kswz(nf * 16 + lr, colk)]);
#pragma unroll
            for (int mi = 0; mi < 2; ++mi)
#pragma unroll
                for (int nf = 0; nf < 4; ++nf)
                    sacc[mi][nf] = __builtin_amdgcn_mfma_f32_16x16x32_bf16(qf[mi][kk], bfr[nf], sacc[mi][nf], 0, 0, 0);
        }

#pragma unroll
        for (int mi = 0; mi < 2; ++mi) {
#pragma unroll
            for (int r = 0; r < 4; ++r) {
                float rowmax = -__builtin_inff();
#pragma unroll
                for (int nf = 0; nf < 4; ++nf) rowmax = fmaxf(rowmax, sacc[mi][nf][r]);
                rowmax *= SCALE;
#pragma unroll
                for (int off = 1; off < 16; off <<= 1)
                    rowmax = fmaxf(rowmax, __shfl_xor(rowmax, off));
                float mold = m_r[mi][r];
                float mnew = fmaxf(mold, rowmax);
                float corr = exp2f((mold - mnew) * LOG2E);
                float mn2 = mnew * LOG2E;
                float rsum = 0.f;
                int prow = w * 32 + mi * 16 + g * 4 + r;
#pragma unroll
                for (int nf = 0; nf < 4; ++nf) {
                    float p = exp2f(sacc[mi][nf][r] * K1 - mn2);
                    rsum += p;
                    Pl[pswz(prow, nf * 16 + lr)] = f2bf(p);
                }
#pragma unroll
                for (int off = 1; off < 16; off <<= 1)
                    rsum += __shfl_xor(rsum, off);
                l_r[mi][r] = l_r[mi][r] * corr + rsum;
                m_r[mi][r] = mnew;
#pragma unroll
                for (int nf = 0; nf < 8; ++nf) oacc[mi][nf][r] *= corr;
            }
        }
        asm volatile("s_waitcnt lgkmcnt(0)" ::: "memory");

#pragma unroll
        for (int kp = 0; kp < 2; ++kp) {
            int colp = kp * 32 + g * 8;
            short8 pa[2];
#pragma unroll
            for (int mi = 0; mi < 2; ++mi)
                pa[mi] = *reinterpret_cast<const short8*>(&Pl[pswz(w * 32 + mi * 16 + lr, colp)]);
#pragma unroll
            for (int nf = 0; nf < 8; ++nf) {
                short8 vb = *reinterpret_cast<const short8*>(&Vt[vswz(nf * 16 + lr, colp)]);
#pragma unroll
                for (int mi = 0; mi < 2; ++mi)
                    oacc[mi][nf] = __builtin_amdgcn_mfma_f32_16x16x32_bf16(pa[mi], vb, oacc[mi][nf], 0, 0, 0);
            }
        }
        __syncthreads();
    }

#pragma unroll
    for (int mi = 0; mi < 2; ++mi)
#pragma unroll
        for (int r = 0; r < 4; ++r) {
            float inv = 1.f / l_r[mi][r];
            int q = qt * 128 + w * 32 + mi * 16 + g * 4 + r;
            size_t base = (size_t)(b * 512 + q) * 1024 + h * 128;
#pragma unroll
            for (int nf = 0; nf < 8; ++nf) {
                int d = nf * 16 + lr;
                out[base + d] = hidden[base + d] + oacc[mi][nf][r] * inv;
            }
        }
}

// -------------------------------------------- fallback (round-1 path) ----
__global__ __launch_bounds__(256) void stats_kernel(
    const float* __restrict__ hidden, const float* __restrict__ inputs,
    float2* __restrict__ statsH, float2* __restrict__ statsX)
{
    int row = blockIdx.x * 4 + (threadIdx.x >> 6);
    int lane = threadIdx.x & 63;
    const float* src; float2* dst;
    if (row < 4096) { src = hidden + (size_t)row * 1024; dst = statsH + row; }
    else            { src = inputs + (size_t)(row - 4096) * 1024; dst = statsX + (row - 4096); }
    float s = 0.f, ss = 0.f;
#pragma unroll
    for (int i = 0; i < 4; ++i) {
        f32x4 v = *reinterpret_cast<const f32x4*>(src + i * 256 + lane * 4);
#pragma unroll
        for (int j = 0; j < 4; ++j) { s += v[j]; ss += v[j] * v[j]; }
    }
#pragma unroll
    for (int off = 32; off >= 1; off >>= 1) { s += __shfl_xor(s, off); ss += __shfl_xor(ss, off); }
    if (lane == 0) {
        float mu = s * (1.f / 1024.f);
        float var = fmaxf(ss * (1.f / 1024.f) - mu * mu, 0.f);
        float2 r; r.x = mu; r.y = rsqrtf(var + 1e-5f);
        *dst = r;
    }
}

DEV int swz64(int row, int col) { return (row * 64 + col) ^ ((row & 7) << 3); }

__global__ __launch_bounds__(256) void gemm_ln(
    const float* __restrict__ A, const float2* __restrict__ stats,
    const float* __restrict__ lnw, const float* __restrict__ lnb,
    const unsigned short* __restrict__ W0, const float* __restrict__ bias0, unsigned short* __restrict__ C0,
    const unsigned short* __restrict__ W1, const float* __restrict__ bias1, unsigned short* __restrict__ C1,
    int nsplit)
{
    __shared__ __align__(16) unsigned short smem[16384];
    unsigned short* Al = smem;
    unsigned short* Bl = smem + 8192;
    int t = threadIdx.x, lane = t & 63, wvi = t >> 6;
    int wr = wvi >> 1, wc = wvi & 1, g = lane >> 4, lr = lane & 15;
    int m0 = blockIdx.x * 128;
    int by = blockIdx.y;
    const unsigned short* W; const float* bias; unsigned short* C; int n0;
    if (by < nsplit) { W = W0; bias = bias0; C = C0; n0 = by * 128; }
    else             { W = W1; bias = bias1; C = C1; n0 = (by - nsplit) * 128; }
    f32x4 acc[4][4];
#pragma unroll
    for (int i = 0; i < 4; ++i)
#pragma unroll
        for (int j = 0; j < 4; ++j) acc[i][j] = (f32x4)0.f;
    int srow = t >> 3, scol = (t & 7) * 8;
    for (int kb = 0; kb < 1024; kb += 64) {
        f32x4 w0 = *reinterpret_cast<const f32x4*>(lnw + kb + scol);
        f32x4 w1 = *reinterpret_cast<const f32x4*>(lnw + kb + scol + 4);
        f32x4 b0 = *reinterpret_cast<const f32x4*>(lnb + kb + scol);
        f32x4 b1 = *reinterpret_cast<const f32x4*>(lnb + kb + scol + 4);
#pragma unroll
        for (int i = 0; i < 4; ++i) {
            int row = i * 32 + srow;
            const float* src = A + (size_t)(m0 + row) * 1024 + kb + scol;
            f32x4 a0 = *reinterpret_cast<const f32x4*>(src);
            f32x4 a1 = *reinterpret_cast<const f32x4*>(src + 4);
            float2 st = stats[m0 + row];
            short8 v;
#pragma unroll
            for (int j = 0; j < 4; ++j) {
                v[j]     = (short)f2bf((a0[j] - st.x) * st.y * w0[j] + b0[j]);
                v[j + 4] = (short)f2bf((a1[j] - st.x) * st.y * w1[j] + b1[j]);
            }
            *reinterpret_cast<short8*>(&Al[swz64(row, scol)]) = v;
        }
#pragma unroll
        for (int i = 0; i < 4; ++i) {
            int row = i * 32 + srow;
            short8 wv8 = *reinterpret_cast<const short8*>(W + (size_t)(n0 + row) * 1024 + kb + scol);
            *reinterpret_cast<short8*>(&Bl[swz64(row, scol)]) = wv8;
        }
        __syncthreads();
#pragma unroll
        for (int kk = 0; kk < 2; ++kk) {
            int colk = kk * 32 + g * 8;
            short8 af[4], bfv[4];
#pragma unroll
            for (int mi = 0; mi < 4; ++mi)
                af[mi] = *reinterpret_cast<const short8*>(&Al[swz64(wr * 64 + mi * 16 + lr, colk)]);
#pragma unroll
            for (int ni = 0; ni < 4; ++ni)
                bfv[ni] = *reinterpret_cast<const short8*>(&Bl[swz64(wc * 64 + ni * 16 + lr, colk)]);
#pragma unroll
            for (int mi = 0; mi < 4; ++mi)
#pragma unroll
                for (int ni = 0; ni < 4; ++ni)
                    acc[mi][ni] = __builtin_amdgcn_mfma_f32_16x16x32_bf16(af[mi], bfv[ni], acc[mi][ni], 0, 0, 0);
        }
        __syncthreads();
    }
    unsigned short* Ct = smem;
#pragma unroll
    for (int ni = 0; ni < 4; ++ni) {
        int coll = wc * 64 + ni * 16 + lr;
        float bv = bias[n0 + coll];
#pragma unroll
        for (int mi = 0; mi < 4; ++mi)
#pragma unroll
            for (int j = 0; j < 4; ++j) {
                int rowl = wr * 64 + mi * 16 + g * 4 + j;
                Ct[rowl * 128 + coll] = f2bf(acc[mi][ni][j] + bv);
            }
    }
    __syncthreads();
#pragma unroll
    for (int i = 0; i < 8; ++i) {
        int idx = i * 2048 + t * 8;
        int row = idx >> 7, col = idx & 127;
        *reinterpret_cast<short8*>(C + (size_t)(m0 + row) * 1024 + n0 + col) =
            *reinterpret_cast<const short8*>(&Ct[idx]);
    }
}

// ---------------------------------------------------------------- host ----
extern "C" void kernel_launch(void* const* d_in, const int* in_sizes, int n_in,
                              void* d_out, int out_size, void* d_ws, size_t ws_size,
                              hipStream_t stream) {
    const float* hidden = (const float*)d_in[0];
    const float* inputs = (const float*)d_in[1];
    const float* ln1w   = (const float*)d_in[2];
    const float* ln1b   = (const float*)d_in[3];
    const float* ln2w   = (const float*)d_in[4];
    const float* ln2b   = (const float*)d_in[5];
    const float* Wq     = (const float*)d_in[6];
    const float* bq     = (const float*)d_in[7];
    const float* Wk     = (const float*)d_in[8];
    const float* bk     = (const float*)d_in[9];
    const float* Wv     = (const float*)d_in[10];
    const float* bv     = (const float*)d_in[11];
    float* out = (float*)d_out;
    char* ws = (char*)d_ws;

    const size_t NEED = 224395264ull;   // big path footprint
    if (ws_size >= NEED) {
        unsigned short* LNh = (unsigned short*)ws;        // 4096x1024
        unsigned short* LNx = LNh + 4194304;              // 32768x1024
        unsigned short* WqB = LNx + 33554432;
        unsigned short* WkB = WqB + 1048576;
        unsigned short* WvB = WkB + 1048576;
        unsigned short* Qm  = WvB + 1048576;              // 4096x1024
        unsigned short* Km  = Qm + 4194304;               // 32768x1024
        unsigned short* Vm  = Km + 33554432;              // 32768x1024

        ln_bf16<<<dim3(9216), dim3(256), 0, stream>>>(hidden, inputs, ln1w, ln1b, ln2w, ln2b, LNh, LNx);
        convert_w<<<dim3(1536), dim3(256), 0, stream>>>(Wq, Wk, Wv, WqB, WkB, WvB);
        gemm_bt<<<dim3(32, 8), dim3(256), 0, stream>>>(LNh, WqB, bq, Qm, WqB, bq, Qm, 8);
        gemm_bt<<<dim3(256, 16), dim3(256), 0, stream>>>(LNx, WkB, bk, Km, WvB, bv, Vm, 8);
        attn_kernel<<<dim3(4, 8, 8), dim3(256), 0, stream>>>(Qm, Km, Vm, hidden, out);
    } else {
        float2* statsH = (float2*)ws;
        float2* statsX = (float2*)(ws + 32768);
        unsigned short* WqB = (unsigned short*)(ws + 294912);
        unsigned short* WkB = WqB + 1048576;
        unsigned short* WvB = WkB + 1048576;
        unsigned short* Qm  = WvB + 1048576;
        unsigned short* Km  = Qm + 4194304;
        unsigned short* Vm  = Km + 33554432;

        stats_kernel<<<dim3(9216), dim3(256), 0, stream>>>(hidden, inputs, statsH, statsX);
        convert_w<<<dim3(1536), dim3(256), 0, stream>>>(Wq, Wk, Wv, WqB, WkB, WvB);
        gemm_ln<<<dim3(32, 8), dim3(256), 0, stream>>>(
            hidden, statsH, ln1w, ln1b, WqB, bq, Qm, WqB, bq, Qm, 8);
        gemm_ln<<<dim3(256, 16), dim3(256), 0, stream>>>(
            inputs, statsX, ln2w, ln2b, WkB, bk, Km, WvB, bv, Vm, 8);
        attn_kernel<<<dim3(4, 8, 8), dim3(256), 0, stream>>>(Qm, Km, Vm, hidden, out);
    }
}

// Round 4
// 406.334 us; speedup vs baseline: 1.4673x; 1.1332x over previous
//
#include <hip/hip_runtime.h>

typedef __attribute__((ext_vector_type(8))) short short8;
typedef __attribute__((ext_vector_type(4))) short bf16x4;
typedef __attribute__((ext_vector_type(4))) float f32x4;

#define DEV __device__ __forceinline__

DEV unsigned short f2bf(float f) {
    unsigned int u = __builtin_bit_cast(unsigned int, f);
    u += 0x7fffu + ((u >> 16) & 1u);
    return (unsigned short)(u >> 16);
}

#define GLOAD16(gp, lp)                                                        \
    __builtin_amdgcn_global_load_lds(                                          \
        (const __attribute__((address_space(1))) void*)(gp),                   \
        (__attribute__((address_space(3))) void*)(lp), 16, 0, 0)

// ------------------------------------------------------------- ln_bf16 ----
__global__ __launch_bounds__(256) void ln_bf16(
    const float* __restrict__ hidden, const float* __restrict__ inputs,
    const float* __restrict__ ln1w, const float* __restrict__ ln1b,
    const float* __restrict__ ln2w, const float* __restrict__ ln2b,
    unsigned short* __restrict__ LNh, unsigned short* __restrict__ LNx)
{
    int row = blockIdx.x * 4 + (threadIdx.x >> 6);
    int lane = threadIdx.x & 63;
    const float *src, *wp, *bp; unsigned short* dst;
    if (row < 4096) { src = hidden + (size_t)row * 1024; wp = ln1w; bp = ln1b; dst = LNh + (size_t)row * 1024; }
    else { int r = row - 4096; src = inputs + (size_t)r * 1024; wp = ln2w; bp = ln2b; dst = LNx + (size_t)r * 1024; }

    f32x4 v[4];
    float s = 0.f, ss = 0.f;
#pragma unroll
    for (int i = 0; i < 4; ++i) {
        v[i] = *reinterpret_cast<const f32x4*>(src + i * 256 + lane * 4);
#pragma unroll
        for (int j = 0; j < 4; ++j) { s += v[i][j]; ss += v[i][j] * v[i][j]; }
    }
#pragma unroll
    for (int off = 32; off >= 1; off >>= 1) { s += __shfl_xor(s, off); ss += __shfl_xor(ss, off); }
    float mu = s * (1.f / 1024.f);
    float var = fmaxf(ss * (1.f / 1024.f) - mu * mu, 0.f);
    float rs = rsqrtf(var + 1e-5f);
#pragma unroll
    for (int i = 0; i < 4; ++i) {
        f32x4 wv = *reinterpret_cast<const f32x4*>(wp + i * 256 + lane * 4);
        f32x4 bv = *reinterpret_cast<const f32x4*>(bp + i * 256 + lane * 4);
        bf16x4 o;
#pragma unroll
        for (int j = 0; j < 4; ++j) o[j] = (short)f2bf((v[i][j] - mu) * rs * wv[j] + bv[j]);
        *reinterpret_cast<bf16x4*>(dst + i * 256 + lane * 4) = o;
    }
}

// ------------------------------------------------------------- convert ----
__global__ __launch_bounds__(256) void convert_w(
    const float* __restrict__ Wq, const float* __restrict__ Wk, const float* __restrict__ Wv,
    unsigned short* __restrict__ oq, unsigned short* __restrict__ ok_, unsigned short* __restrict__ ov)
{
    unsigned tid = blockIdx.x * 256 + threadIdx.x;
    int arr = tid >> 17;
    size_t off = (size_t)(tid & 131071u) * 8;
    const float* s = (arr == 0) ? Wq : (arr == 1) ? Wk : Wv;
    unsigned short* d = (arr == 0) ? oq : (arr == 1) ? ok_ : ov;
    f32x4 a = *reinterpret_cast<const f32x4*>(s + off);
    f32x4 b = *reinterpret_cast<const f32x4*>(s + off + 4);
    short8 r;
#pragma unroll
    for (int j = 0; j < 4; ++j) { r[j] = (short)f2bf(a[j]); r[j + 4] = (short)f2bf(b[j]); }
    *reinterpret_cast<short8*>(d + off) = r;
}

// ---------------------------------------------------------------- GEMM ----
// C[m,n] = sum_k A[m,k] * W[n,k] + bias[n]; 128x128 tile, BK=64, m97 structure.
// tmode=1: the by>=nsplit (V) output is written TRANSPOSED per head:
//          C1[((b*8+h)*128 + d)*4096 + kv]  (b = m/4096, kv = m%4096, d = n%128)
__global__ __launch_bounds__(256) void gemm_bt(
    const unsigned short* __restrict__ A,
    const unsigned short* __restrict__ W0, const float* __restrict__ bias0, unsigned short* __restrict__ C0,
    const unsigned short* __restrict__ W1, const float* __restrict__ bias1, unsigned short* __restrict__ C1,
    int nsplit, int tmode)
{
    __shared__ __align__(16) unsigned short smem[17408];   // As[128][64]+Bs[128][64]; Ct[128][128]; Ct_t[128][136]
    unsigned short* As = smem;
    unsigned short* Bs = smem + 8192;

    int t = threadIdx.x, lane = t & 63, w = t >> 6;
    int wr = w >> 1, wc = w & 1, g = lane >> 4, lr = lane & 15;
    int m0 = blockIdx.x * 128;
    int by = blockIdx.y;
    const unsigned short* W; const float* bias; unsigned short* C; int n0; int tp;
    if (by < nsplit) { W = W0; bias = bias0; C = C0; n0 = by * 128; tp = 0; }
    else             { W = W1; bias = bias1; C = C1; n0 = (by - nsplit) * 128; tp = tmode; }

    f32x4 acc[4][4];
#pragma unroll
    for (int i = 0; i < 4; ++i)
#pragma unroll
        for (int j = 0; j < 4; ++j) acc[i][j] = (f32x4)0.f;

    int srow = lane >> 3;
    int scb  = (lane & 7) * 16;

    for (int kb = 0; kb < 1024; kb += 64) {
#pragma unroll
        for (int i = 0; i < 4; ++i) {
            int row = i * 32 + w * 8 + srow;
            int cb = scb ^ ((row & 7) << 4);
            const char* ga = (const char*)(A + (size_t)(m0 + row) * 1024 + kb) + cb;
            GLOAD16(ga, &As[(size_t)(i * 32 + w * 8) * 64]);
            const char* gb = (const char*)(W + (size_t)(n0 + row) * 1024 + kb) + cb;
            GLOAD16(gb, &Bs[(size_t)(i * 32 + w * 8) * 64]);
        }
        __syncthreads();
#pragma unroll
        for (int kk = 0; kk < 2; ++kk) {
            int cb0 = kk * 64 + g * 16;
            short8 af[4], bf[4];
#pragma unroll
            for (int mi = 0; mi < 4; ++mi) {
                int row = wr * 64 + mi * 16 + lr;
                af[mi] = *reinterpret_cast<const short8*>(
                    (const char*)As + row * 128 + (cb0 ^ ((row & 7) << 4)));
            }
#pragma unroll
            for (int ni = 0; ni < 4; ++ni) {
                int row = wc * 64 + ni * 16 + lr;
                bf[ni] = *reinterpret_cast<const short8*>(
                    (const char*)Bs + row * 128 + (cb0 ^ ((row & 7) << 4)));
            }
#pragma unroll
            for (int mi = 0; mi < 4; ++mi)
#pragma unroll
                for (int ni = 0; ni < 4; ++ni)
                    acc[mi][ni] = __builtin_amdgcn_mfma_f32_16x16x32_bf16(af[mi], bf[ni], acc[mi][ni], 0, 0, 0);
        }
        __syncthreads();
    }

    if (tp) {
        // transposed epilogue: Ct_t[d][kv], stride 136 (272B rows: 16B-aligned, 2-way banks)
        unsigned short* Ct = smem;
#pragma unroll
        for (int ni = 0; ni < 4; ++ni) {
            int coll = wc * 64 + ni * 16 + lr;
            float bv = bias[n0 + coll];
#pragma unroll
            for (int mi = 0; mi < 4; ++mi)
#pragma unroll
                for (int j = 0; j < 4; ++j) {
                    int rowl = wr * 64 + mi * 16 + g * 4 + j;
                    Ct[coll * 136 + rowl] = f2bf(acc[mi][ni][j] + bv);
                }
        }
        __syncthreads();
        int bb = m0 >> 12, kv0 = m0 & 4095, h = by - nsplit;
        unsigned short* Cb = C + (((size_t)(bb * 8 + h)) * 128) * 4096 + kv0;
#pragma unroll
        for (int i = 0; i < 8; ++i) {
            int idx = i * 2048 + t * 8;
            int d = idx >> 7, kvl = idx & 127;
            *reinterpret_cast<short8*>(Cb + (size_t)d * 4096 + kvl) =
                *reinterpret_cast<const short8*>(&Ct[d * 136 + kvl]);
        }
    } else {
        unsigned short* Ct = smem;
#pragma unroll
        for (int ni = 0; ni < 4; ++ni) {
            int coll = wc * 64 + ni * 16 + lr;
            float bv = bias[n0 + coll];
#pragma unroll
            for (int mi = 0; mi < 4; ++mi)
#pragma unroll
                for (int j = 0; j < 4; ++j) {
                    int rowl = wr * 64 + mi * 16 + g * 4 + j;
                    Ct[rowl * 128 + coll] = f2bf(acc[mi][ni][j] + bv);
                }
        }
        __syncthreads();
#pragma unroll
        for (int i = 0; i < 8; ++i) {
            int idx = i * 2048 + t * 8;
            int row = idx >> 7, col = idx & 127;
            *reinterpret_cast<short8*>(C + (size_t)(m0 + row) * 1024 + n0 + col) =
                *reinterpret_cast<const short8*>(&Ct[idx]);
        }
    }
}

// ----------------------------------------------------------- attention ----
// 8 waves x 16 q-rows (128-q tile), KVBLK=64, double-buffered gload_lds K/Vt,
// one barrier per chunk. V comes pre-transposed from the GEMM (VtG[b][h][d][kv]).
__global__ __launch_bounds__(512, 1) void attn_kernel(
    const unsigned short* __restrict__ Qm, const unsigned short* __restrict__ Km,
    const unsigned short* __restrict__ VtG, const float* __restrict__ hidden,
    float* __restrict__ out)
{
    __shared__ __align__(16) unsigned short Kl[2][64 * 128];
    __shared__ __align__(16) unsigned short Vt[2][128 * 64];
    __shared__ __align__(16) unsigned short Pl[128 * 64];

    int t = threadIdx.x, lane = t & 63, w = t >> 6, g = lane >> 4, lr = lane & 15;
    // XCD-aware swizzle: 256 blocks, 8 XCDs; same-b group contiguous per XCD;
    // same (b,h)'s 4 q-tiles adjacent -> share XCD L2 (K+V = 4MB).
    int swz = (blockIdx.x & 7) * 32 + (blockIdx.x >> 3);
    int qt = swz & 3, h = (swz >> 2) & 7, b = swz >> 5;

    short8 qf[4];
#pragma unroll
    for (int kk = 0; kk < 4; ++kk)
        qf[kk] = *reinterpret_cast<const short8*>(
            Qm + (size_t)(b * 512 + qt * 128 + w * 16 + lr) * 1024 + h * 128 + kk * 32 + g * 8);

    float m_r[4], l_r[4];
    f32x4 oacc[8];
#pragma unroll
    for (int j = 0; j < 4; ++j) { m_r[j] = -__builtin_inff(); l_r[j] = 0.f; }
#pragma unroll
    for (int nf = 0; nf < 8; ++nf) oacc[nf] = (f32x4)0.f;

    const float SCALE = 0.08838834764831845f;   // 1/sqrt(128)
    const float LOG2E = 1.4426950408889634f;
    const float K1 = SCALE * LOG2E;

    size_t kbase = (size_t)b * 4096 * 1024 + h * 128;     // K row elements
    size_t vbase = ((size_t)(b * 8 + h)) * 128 * 4096;    // VtG d-row elements

    auto STAGE = [&](int buf, int c) {
        int kv0 = c * 64;
#pragma unroll
        for (int i = 0; i < 2; ++i) {                     // K: 4 kv-rows per instr
            int row = w * 8 + i * 4 + (lane >> 4);
            int cb = ((lane & 15) * 16) ^ ((row & 7) << 4);
            const char* gp = (const char*)(Km + kbase + (size_t)(kv0 + row) * 1024) + cb;
            GLOAD16(gp, &Kl[buf][(w * 8 + i * 4) * 128]);
        }
#pragma unroll
        for (int i = 0; i < 2; ++i) {                     // Vt: 8 d-rows per instr
            int d = w * 16 + i * 8 + (lane >> 3);
            int cb = ((lane & 7) * 16) ^ ((d & 7) << 4);
            const char* gp = (const char*)(VtG + vbase + (size_t)d * 4096 + kv0) + cb;
            GLOAD16(gp, &Vt[buf][(w * 16 + i * 8) * 64]);
        }
    };

    STAGE(0, 0);
    for (int c = 0; c < 64; ++c) {
        int cur = c & 1;
        __syncthreads();                                   // buf[cur] landed; buf[cur^1] free
        if (c < 63) STAGE(cur ^ 1, c + 1);                 // prefetch under compute

        // S = Q K^T : 16 q x 64 kv per wave
        f32x4 sacc[4];
#pragma unroll
        for (int nf = 0; nf < 4; ++nf) sacc[nf] = (f32x4)0.f;
#pragma unroll
        for (int kk = 0; kk < 4; ++kk) {
            int cb0 = kk * 64 + g * 16;
            short8 bfr[4];
#pragma unroll
            for (int nf = 0; nf < 4; ++nf) {
                int row = nf * 16 + lr;
                bfr[nf] = *reinterpret_cast<const short8*>(
                    (const char*)&Kl[cur][0] + row * 256 + (cb0 ^ ((row & 7) << 4)));
            }
#pragma unroll
            for (int nf = 0; nf < 4; ++nf)
                sacc[nf] = __builtin_amdgcn_mfma_f32_16x16x32_bf16(qf[kk], bfr[nf], sacc[nf], 0, 0, 0);
        }

        // online softmax; rows j: q_local = w*16 + g*4 + j
#pragma unroll
        for (int j = 0; j < 4; ++j) {
            float rowmax = fmaxf(fmaxf(sacc[0][j], sacc[1][j]), fmaxf(sacc[2][j], sacc[3][j]));
            rowmax *= SCALE;
#pragma unroll
            for (int off = 1; off < 16; off <<= 1)
                rowmax = fmaxf(rowmax, __shfl_xor(rowmax, off));
            float mold = m_r[j];
            float mnew = fmaxf(mold, rowmax);
            float corr = exp2f((mold - mnew) * LOG2E);
            float mn2 = mnew * LOG2E;
            float rsum = 0.f;
            int prow = w * 16 + g * 4 + j;
            int rswz = (prow & 7) << 4;
#pragma unroll
            for (int nf = 0; nf < 4; ++nf) {
                float p = exp2f(sacc[nf][j] * K1 - mn2);
                rsum += p;
                *reinterpret_cast<unsigned short*>(
                    (char*)Pl + prow * 128 + ((nf * 32 + lr * 2) ^ rswz)) = f2bf(p);
            }
#pragma unroll
            for (int off = 1; off < 16; off <<= 1)
                rsum += __shfl_xor(rsum, off);
            l_r[j] = l_r[j] * corr + rsum;
            m_r[j] = mnew;
#pragma unroll
            for (int nf = 0; nf < 8; ++nf) oacc[nf][j] *= corr;
        }

        // O += P V : each wave reads only its own 16 Pl rows (no barrier needed)
#pragma unroll
        for (int kp = 0; kp < 2; ++kp) {
            int cb0 = kp * 64 + g * 16;
            int prow = w * 16 + lr;
            short8 pa = *reinterpret_cast<const short8*>(
                (const char*)Pl + prow * 128 + (cb0 ^ ((prow & 7) << 4)));
#pragma unroll
            for (int nf = 0; nf < 8; ++nf) {
                int d = nf * 16 + lr;
                short8 vb = *reinterpret_cast<const short8*>(
                    (const char*)&Vt[cur][0] + d * 128 + (cb0 ^ ((d & 7) << 4)));
                oacc[nf] = __builtin_amdgcn_mfma_f32_16x16x32_bf16(pa, vb, oacc[nf], 0, 0, 0);
            }
        }
    }

    // epilogue: out = hidden + O / l
#pragma unroll
    for (int j = 0; j < 4; ++j) {
        float inv = 1.f / l_r[j];
        int q = qt * 128 + w * 16 + g * 4 + j;
        size_t base = (size_t)(b * 512 + q) * 1024 + h * 128;
#pragma unroll
        for (int nf = 0; nf < 8; ++nf) {
            int d = nf * 16 + lr;
            out[base + d] = hidden[base + d] + oacc[nf][j] * inv;
        }
    }
}

// ---------------------------------------------------------------- host ----
extern "C" void kernel_launch(void* const* d_in, const int* in_sizes, int n_in,
                              void* d_out, int out_size, void* d_ws, size_t ws_size,
                              hipStream_t stream) {
    const float* hidden = (const float*)d_in[0];
    const float* inputs = (const float*)d_in[1];
    const float* ln1w   = (const float*)d_in[2];
    const float* ln1b   = (const float*)d_in[3];
    const float* ln2w   = (const float*)d_in[4];
    const float* ln2b   = (const float*)d_in[5];
    const float* Wq     = (const float*)d_in[6];
    const float* bq     = (const float*)d_in[7];
    const float* Wk     = (const float*)d_in[8];
    const float* bk     = (const float*)d_in[9];
    const float* Wv     = (const float*)d_in[10];
    const float* bv     = (const float*)d_in[11];
    float* out = (float*)d_out;
    char* ws = (char*)d_ws;

    unsigned short* LNh = (unsigned short*)ws;        // 4096x1024 bf16
    unsigned short* LNx = LNh + 4194304;              // 32768x1024
    unsigned short* WqB = LNx + 33554432;             // 3 x 1024x1024
    unsigned short* WkB = WqB + 1048576;
    unsigned short* WvB = WkB + 1048576;
    unsigned short* Qm  = WvB + 1048576;              // 4096x1024
    unsigned short* Km  = Qm + 4194304;               // 32768x1024
    unsigned short* VtG = Km + 33554432;              // [b][h][128 d][4096 kv]

    ln_bf16<<<dim3(9216), dim3(256), 0, stream>>>(hidden, inputs, ln1w, ln1b, ln2w, ln2b, LNh, LNx);
    convert_w<<<dim3(1536), dim3(256), 0, stream>>>(Wq, Wk, Wv, WqB, WkB, WvB);
    gemm_bt<<<dim3(32, 8), dim3(256), 0, stream>>>(LNh, WqB, bq, Qm, WqB, bq, Qm, 8, 0);
    gemm_bt<<<dim3(256, 16), dim3(256), 0, stream>>>(LNx, WkB, bk, Km, WvB, bv, VtG, 8, 1);
    attn_kernel<<<dim3(256), dim3(512), 0, stream>>>(Qm, Km, VtG, hidden, out);
}